// Round 3
// baseline (1227.188 us; speedup 1.0000x reference)
//
#include <hip/hip_runtime.h>

#define DEV __device__ __forceinline__

typedef float f32x4 __attribute__((ext_vector_type(4)));
typedef short s16x8 __attribute__((ext_vector_type(8)));
typedef short s16x4 __attribute__((ext_vector_type(4)));

// ---------- scalar helpers ----------
DEV unsigned short f2bf(float f){
  unsigned int u = __float_as_uint(f);
  u += 0x7fffu + ((u>>16)&1u);
  return (unsigned short)(u>>16);
}
DEV float bf2f(unsigned short h){ return __uint_as_float(((unsigned int)h)<<16); }

#if __has_builtin(__builtin_amdgcn_rcpf)
DEV float frcp_(float x){ return __builtin_amdgcn_rcpf(x); }
#else
DEV float frcp_(float x){ return 1.f/x; }
#endif
#if __has_builtin(__builtin_amdgcn_exp2f)
DEV float fexp2_(float x){ return __builtin_amdgcn_exp2f(x); }
#else
DEV float fexp2_(float x){ return exp2f(x); }
#endif

DEV float sigm(float x){ return frcp_(1.f + fexp2_(-1.4426950408889634f*x)); }
DEV float tanh_(float x){
  x = fminf(x, 30.f);                       // overflow guard
  float e = fexp2_(2.8853900817779268f*x);
  return (e-1.f)*frcp_(e+1.f);
}

DEV f32x4 mfma_bf16(s16x8 a, s16x8 b, f32x4 c){
  return __builtin_amdgcn_mfma_f32_16x16x32_bf16(a,b,c,0,0,0);
}

// ---------- problem constants ----------
#define Bx 128
#define Vx 64
#define Sx 40
#define Dx 256
#define Hx 256

// d_out element offsets (f32)
#define OFF_OG   0
#define OFF_FAKE 256
#define OFF_DECV 512
#define OFF_GENV 2097664      // 512 + 128*64*256
#define OFF_STS  4194816      // OFF_GENV + 128*64*256
#define OFF_LBL  4203008      // OFF_STS + 8192

// bf16 weight-pool element offsets
#define PW_IH  0
#define PW_HH  262144
#define PW_HK  524288
#define PW_1   589824
#define PC_1   622592
#define PC_2   884736
#define PC_O   1409024
#define P_TOT  1410048

// ---------- K0: convert all f32 weight matrices to bf16 pool ----------
__global__ void k_cvtall(const float* __restrict__ W_ih, const float* __restrict__ Whh,
                         const float* __restrict__ Whk, const float* __restrict__ W1,
                         const float* __restrict__ C1W, const float* __restrict__ C2W,
                         const float* __restrict__ CoW, unsigned short* __restrict__ dst){
  int i = blockIdx.x*256 + threadIdx.x;
  float v;
  if      (i < PW_HH) v = W_ih[i - PW_IH];
  else if (i < PW_HK) v = Whh [i - PW_HH];
  else if (i < PW_1 ) v = Whk [i - PW_HK];
  else if (i < PC_1 ) v = W1  [i - PW_1 ];
  else if (i < PC_2 ) v = C1W [i - PC_1 ];
  else if (i < PC_O ) v = C2W [i - PC_2 ];
  else if (i < P_TOT) v = CoW [i - PC_O ];
  else return;
  dst[i] = f2bf(v);
}

// ---------- K1: v = sum_s relu(emb[idx]) ; dual-store; Dec/Gen row 0 ----------
__global__ void k_embed(const int* __restrict__ seqs, const float* __restrict__ emb,
                        float* __restrict__ v32, unsigned short* __restrict__ v16,
                        float* __restrict__ decv, float* __restrict__ genv,
                        unsigned short* __restrict__ barv16){
  int bt = blockIdx.x;          // b*64 + t
  int d = threadIdx.x;
  const int* sp = seqs + (size_t)bt*Sx;
  float acc = 0.f;
  #pragma unroll 4
  for (int s=0;s<Sx;s++){
    int id = sp[s];
    acc += fmaxf(emb[(size_t)id*Dx + d], 0.f);
  }
  size_t o = (size_t)bt*Dx + d;
  v32[o] = acc;
  v16[o] = f2bf(acc);
  if ((bt & 63) == 0){          // t == 0: bar_v row 0 = v[:,0,:]
    decv[o] = acc; genv[o] = acc; barv16[o] = f2bf(acc);
  }
}

// ---------- generic MFMA GEMM: C[M,N] = A[M,K] * Bw[N,K]^T + bias1 + bias2 ----------
// MODE_A: 0 = A row-major rows m (pitch K); 1 = v-layout [b][t][d], m = t*128+b
// MODE_C: 0 = row-major [m][n] bf16 (pitch Ntot) + optional f32 copy; 1 = xg layout [t][n][b]
template<int MODE_A, int MODE_C>
__global__ void k_gemm(const unsigned short* __restrict__ A, const unsigned short* __restrict__ Bw,
                       const float* __restrict__ bias1, const float* __restrict__ bias2,
                       unsigned short* __restrict__ C, float* __restrict__ C32,
                       int K, int Ntot){
  int tid = threadIdx.x, w = tid>>6, l = tid&63, lm = l&15, q = l>>4;
  int m0 = blockIdx.x*64;
  int n0 = blockIdx.y*256 + w*64;
  f32x4 acc[4][4];
  #pragma unroll
  for (int nt=0;nt<4;nt++){
    int n = n0 + nt*16 + lm;
    float bz = bias1 ? bias1[n] : 0.f;
    if (bias2) bz += bias2[n];
    #pragma unroll
    for (int mt=0;mt<4;mt++) acc[mt][nt] = (f32x4){bz,bz,bz,bz};
  }
  const s16x8* Arow[4];
  #pragma unroll
  for (int mt=0;mt<4;mt++){
    int m = m0 + mt*16 + lm;
    size_t off = (MODE_A==0) ? (size_t)m*K : ((size_t)(m&127)*Vx + (m>>7))*(size_t)K;
    Arow[mt] = (const s16x8*)(A + off);
  }
  int kkn = K/32;
  for (int kk=0; kk<kkn; kk++){
    s16x8 bfr[4];
    #pragma unroll
    for (int nt=0;nt<4;nt++){
      int n = n0 + nt*16 + lm;
      bfr[nt] = *(const s16x8*)(Bw + (size_t)n*K + kk*32 + q*8);
    }
    #pragma unroll
    for (int mt=0;mt<4;mt++){
      s16x8 afr = Arow[mt][kk*4 + q];
      #pragma unroll
      for (int nt=0;nt<4;nt++)
        acc[mt][nt] = mfma_bf16(afr, bfr[nt], acc[mt][nt]);
    }
  }
  #pragma unroll
  for (int mt=0;mt<4;mt++){
    int mbase = m0 + mt*16 + q*4;
    #pragma unroll
    for (int nt=0;nt<4;nt++){
      int n = n0 + nt*16 + lm;
      if (MODE_C==0){
        #pragma unroll
        for (int r=0;r<4;r++){
          float val = acc[mt][nt][r];
          C[(size_t)(mbase+r)*Ntot + n] = f2bf(val);
          if (C32) C32[(size_t)(mbase+r)*Ntot + n] = val;
        }
      } else {
        int tt = mbase>>7, bb = mbase&127;
        s16x4 sv;
        #pragma unroll
        for (int r=0;r<4;r++) sv[r] = (short)f2bf(acc[mt][nt][r]);
        *(s16x4*)(C + ((size_t)tt*Ntot + n)*Bx + bb) = sv;
      }
    }
  }
}

// ---------- K3/K7: LSTM scan, bf16 MFMA. 8 blocks x 1024 thr; 16 batch rows/block ----------
#define HP 264   // LDS pitch in shorts
template<int STORE_ALL>
__global__ __launch_bounds__(1024) void k_scan(const unsigned short* __restrict__ Whh,
        const unsigned short* __restrict__ xg, unsigned short* __restrict__ hist){
  __shared__ __align__(16) unsigned short hl[2][16*HP];
  int tid = threadIdx.x;
  int g = blockIdx.x;                        // batch group: b in [16g, 16g+16)
  int w = tid>>6, l = tid&63, lm = l&15, q = l>>4;
  int j = w*16 + lm;                         // hidden index owned by this lane
  for (int i=tid;i<2*16*HP;i+=1024) ((unsigned short*)hl)[i] = 0;
  s16x8 Bf[4][8];
  #pragma unroll
  for (int qq=0;qq<4;qq++){
    int n = qq*256 + j;
    #pragma unroll
    for (int kk=0;kk<8;kk++)
      Bf[qq][kk] = *(const s16x8*)(Whh + (size_t)n*256 + kk*32 + q*8);
  }
  float cst[4] = {0.f,0.f,0.f,0.f};
  const unsigned short* xgl = xg + (size_t)g*16 + q*4;
  __syncthreads();
  #pragma unroll 1
  for (int t=0;t<Vx;t++){
    f32x4 acc[4];
    #pragma unroll
    for (int qq=0;qq<4;qq++){
      s16x4 xv = *(const s16x4*)(xgl + ((size_t)t*1024 + qq*256 + j)*Bx);
      f32x4 a;
      #pragma unroll
      for (int r=0;r<4;r++) a[r] = bf2f((unsigned short)xv[r]);
      acc[qq] = a;
    }
    const unsigned short* hb = hl[t&1];
    #pragma unroll
    for (int kk=0;kk<8;kk++){
      s16x8 af = *(const s16x8*)(hb + lm*HP + kk*32 + q*8);
      acc[0] = mfma_bf16(af, Bf[0][kk], acc[0]);
      acc[1] = mfma_bf16(af, Bf[1][kk], acc[1]);
      acc[2] = mfma_bf16(af, Bf[2][kk], acc[2]);
      acc[3] = mfma_bf16(af, Bf[3][kk], acc[3]);
    }
    unsigned short* hn = hl[(t+1)&1];
    #pragma unroll
    for (int r=0;r<4;r++){
      float iv = sigm (acc[0][r]);
      float fv = sigm (acc[1][r]);
      float gv = tanh_(acc[2][r]);
      float ov = sigm (acc[3][r]);
      float cv = fv*cst[r] + iv*gv;
      cst[r] = cv;
      float hv = ov*tanh_(cv);
      unsigned short h16 = f2bf(hv);
      hn[(q*4+r)*HP + j] = h16;
      if (STORE_ALL)
        hist[((size_t)t*Bx + g*16 + q*4 + r)*Hx + j] = h16;
      else if (t==Vx-1)
        hist[((size_t)(g*16 + q*4 + r))*Hx + j] = h16;
    }
    __syncthreads();
  }
}

// ---------- K5a: u[b][n] = e_k[b] @ W1[:, :256]^T + b1 (f32) ----------
__global__ void k_u(const float* __restrict__ v32, const float* __restrict__ W1,
                    const float* __restrict__ b1, float* __restrict__ u){
  int b = blockIdx.x, n = threadIdx.x;   // 128 x 64
  const f32x4* vr = (const f32x4*)(v32 + (size_t)b*Vx*Dx);   // v[b][0][:]
  const f32x4* wr = (const f32x4*)(W1 + (size_t)n*512);
  float a = b1[n];
  for (int kk=0;kk<64;kk++){
    f32x4 x = vr[kk], ww = wr[kk];
    a += x[0]*ww[0] + x[1]*ww[1] + x[2]*ww[2] + x[3]*ww[3];
  }
  u[(size_t)b*64 + n] = a;
}

// ---------- K5b: attention + bar_v -> Dec_V/Gen_V rows t'=1..63 ----------
__global__ void k_attn(const unsigned short* __restrict__ wh16, const float* __restrict__ wh32,
                       const float* __restrict__ v32, const float* __restrict__ u,
                       const unsigned short* __restrict__ W116, const float* __restrict__ W2,
                       const float* __restrict__ b2,
                       float* __restrict__ decv, float* __restrict__ genv,
                       unsigned short* __restrict__ barv16){
  int tid = threadIdx.x, w = tid>>6, l = tid&63, lm = l&15, q = l>>4;
  int mt = blockIdx.x*4 + w;            // 504 M-tiles of 16 rows, rows m = t'*128 + b
  int m0 = mt*16;
  f32x4 acc[4];
  #pragma unroll
  for (int nt=0;nt<4;nt++){
    int n = nt*16 + lm;
    f32x4 a;
    #pragma unroll
    for (int r=0;r<4;r++) a[r] = u[(size_t)((m0 + q*4 + r)&127)*64 + n];
    acc[nt] = a;
  }
  const s16x8* Arow = (const s16x8*)(wh16 + (size_t)(m0+lm)*Dx);
  #pragma unroll
  for (int kk=0;kk<8;kk++){
    s16x8 af = Arow[kk*4 + q];
    #pragma unroll
    for (int nt=0;nt<4;nt++){
      int n = nt*16 + lm;
      s16x8 bf = *(const s16x8*)(W116 + (size_t)n*512 + 256 + kk*32 + q*8);
      acc[nt] = mfma_bf16(af, bf, acc[nt]);
    }
  }
  float p0a[4] = {0,0,0,0}, p1a[4] = {0,0,0,0};
  #pragma unroll
  for (int nt=0;nt<4;nt++){
    int n = nt*16 + lm;
    float w2a = W2[n], w2b = W2[64+n];
    #pragma unroll
    for (int r=0;r<4;r++){
      float z = tanh_(acc[nt][r]);
      p0a[r] += z*w2a; p1a[r] += z*w2b;
    }
  }
  #pragma unroll
  for (int s=1;s<16;s<<=1){
    #pragma unroll
    for (int r=0;r<4;r++){ p0a[r] += __shfl_xor(p0a[r], s, 16); p1a[r] += __shfl_xor(p1a[r], s, 16); }
  }
  float bb0 = b2[0], bb1 = b2[1];
  int t = m0>>7;                         // t' (uniform per wave)
  int d0 = lm*16;
  #pragma unroll
  for (int r=0;r<4;r++){
    int m = m0 + q*4 + r; int b = m&127;
    float a0 = p0a[r]+bb0, a1 = p1a[r]+bb1;
    float al0 = frcp_(1.f + fexp2_(1.4426950408889634f*(a1-a0)));  // softmax over {a0,a1}
    float al1 = 1.f - al0;
    const f32x4* ek  = (const f32x4*)(v32  + (size_t)b*Vx*Dx + d0);
    const f32x4* whr = (const f32x4*)(wh32 + (size_t)m*Dx + d0);
    size_t ob = ((size_t)b*Vx + (t+1))*Dx + d0;
    #pragma unroll
    for (int c=0;c<4;c++){
      f32x4 e = ek[c], wv = whr[c], o;
      s16x4 o16;
      #pragma unroll
      for (int jj=0;jj<4;jj++){
        o[jj] = al0*e[jj] + al1*wv[jj];
        o16[jj] = (short)f2bf(o[jj]);
      }
      *(f32x4*)(decv + ob + c*4) = o;
      *(f32x4*)(genv + ob + c*4) = o;
      *(s16x4*)(barv16 + ob + c*4) = o16;
    }
  }
}

// ---------- K8: classifier heads on h1[t=63] and h2 ----------
__global__ void k_classify(const unsigned short* __restrict__ h1, const unsigned short* __restrict__ h2,
    const unsigned short* __restrict__ C1W16, const float* __restrict__ C1b,
    const unsigned short* __restrict__ C2W16, const float* __restrict__ C2b,
    const unsigned short* __restrict__ CoW16, const float* __restrict__ Cob,
    float* __restrict__ out){
  int blk = blockIdx.x;                // 0..255
  int b = blk & 127; bool fake = blk >= 128;
  const unsigned short* X = fake ? (h2 + (size_t)b*Hx) : (h1 + (size_t)b*Hx);
  __shared__ float xs[256]; __shared__ float y1[1024]; __shared__ float y2[512];
  __shared__ float r0[256], r1[256];
  int tid = threadIdx.x;
  xs[tid] = bf2f(X[tid]);
  __syncthreads();
  for (int n = tid; n < 1024; n += 256){
    const s16x8* wr = (const s16x8*)(C1W16 + (size_t)n*256);
    float a = C1b[n];
    for (int kk=0;kk<32;kk++){
      s16x8 ww = wr[kk];
      #pragma unroll
      for (int jj=0;jj<8;jj++) a += xs[kk*8+jj]*bf2f((unsigned short)ww[jj]);
    }
    y1[n] = fmaxf(a, 0.f);
  }
  __syncthreads();
  for (int n = tid; n < 512; n += 256){
    const s16x8* wr = (const s16x8*)(C2W16 + (size_t)n*1024);
    float a = C2b[n];
    for (int kk=0;kk<128;kk++){
      s16x8 ww = wr[kk];
      #pragma unroll
      for (int jj=0;jj<8;jj++) a += y1[kk*8+jj]*bf2f((unsigned short)ww[jj]);
    }
    y2[n] = fmaxf(a, 0.f);
  }
  __syncthreads();
  float p0 = 0.f, p1 = 0.f;
  for (int k = tid; k < 512; k += 256){
    float yv = y2[k];
    p0 += yv*bf2f(CoW16[k]); p1 += yv*bf2f(CoW16[512+k]);
  }
  r0[tid] = p0; r1[tid] = p1; __syncthreads();
  for (int s=128; s>0; s>>=1){
    if (tid < s){ r0[tid] += r0[tid+s]; r1[tid] += r1[tid+s]; }
    __syncthreads();
  }
  if (tid == 0){
    int base = (fake ? OFF_FAKE : OFF_OG) + b*2;
    out[base+0] = r0[0] + Cob[0];
    out[base+1] = r1[0] + Cob[1];
  }
}

// ---------- K9: passthrough outputs ----------
__global__ void k_copy(const float* __restrict__ sts, const int* __restrict__ label,
                       float* __restrict__ out){
  int i = blockIdx.x*256 + threadIdx.x;
  if (i < Bx*Vx) out[OFF_STS + i] = sts[i];
  if (i < Bx)    out[OFF_LBL + i] = (float)label[i];
}

// ---------- launch ----------
extern "C" void kernel_launch(void* const* d_in, const int* in_sizes, int n_in,
                              void* d_out, int out_size, void* d_ws, size_t ws_size,
                              hipStream_t stream) {
  const int*   seqs  = (const int*)d_in[0];
  const float* sts   = (const float*)d_in[3];
  const int*   label = (const int*)d_in[5];
  const float* emb   = (const float*)d_in[6];
  const float* W_ih  = (const float*)d_in[7];
  const float* W_hh  = (const float*)d_in[8];
  const float* b_ih  = (const float*)d_in[9];
  const float* b_hh  = (const float*)d_in[10];
  const float* Whk   = (const float*)d_in[11];
  const float* bhk   = (const float*)d_in[12];
  const float* W1    = (const float*)d_in[13];
  const float* b1    = (const float*)d_in[14];
  const float* W2    = (const float*)d_in[15];
  const float* b2    = (const float*)d_in[16];
  const float* C1b   = (const float*)d_in[18];
  const float* C2b   = (const float*)d_in[20];
  const float* Cob   = (const float*)d_in[22];
  float* out = (float*)d_out;

  char* ws = (char*)d_ws;
  unsigned short* v16    = (unsigned short*)(ws + 0);          //  4 MB  [b][t][d] bf16
  unsigned short* xg     = (unsigned short*)(ws + (4<<20));    // 16 MB  [t][n][b] bf16
  unsigned short* hist1  = (unsigned short*)(ws + (20<<20));   //  4 MB  [t][b][j] bf16
  unsigned short* wh16   = (unsigned short*)(ws + (24<<20));   //  4 MB  [m][d] bf16
  unsigned short* barv16 = (unsigned short*)(ws + (28<<20));   //  4 MB  [b][t][d] bf16
  float*          v32    = (float*)(ws + (32<<20));            //  8 MB  [b][t][d] f32
  float*          wh32   = (float*)(ws + (40<<20));            //  8 MB  [m][d] f32
  float*          u      = (float*)(ws + (48<<20));            // 32 KB  [b][n] f32
  unsigned short* h2     = (unsigned short*)(ws + (48<<20) + 32768);          // 64 KB
  unsigned short* pool   = (unsigned short*)(ws + (48<<20) + 32768 + 65536); // 2.7 MB bf16 weights

  float* decv = out + OFF_DECV;
  float* genv = out + OFF_GENV;

  k_cvtall<<<dim3(5508), dim3(256), 0, stream>>>(W_ih, W_hh, Whk, W1,
      (const float*)d_in[17], (const float*)d_in[19], (const float*)d_in[21], pool);
  k_embed<<<dim3(Bx*Vx), dim3(256), 0, stream>>>(seqs, emb, v32, v16, decv, genv, barv16);
  k_gemm<1,1><<<dim3(128,4), dim3(256), 0, stream>>>(v16, pool+PW_IH, b_ih, b_hh, xg, nullptr, 256, 1024);
  k_scan<1><<<dim3(8), dim3(1024), 0, stream>>>(pool+PW_HH, xg, hist1);
  k_u<<<dim3(128), dim3(64), 0, stream>>>(v32, W1, b1, u);
  k_gemm<0,0><<<dim3(128,1), dim3(256), 0, stream>>>(hist1, pool+PW_HK, bhk, nullptr, wh16, wh32, 256, 256);
  k_attn<<<dim3(126), dim3(256), 0, stream>>>(wh16, wh32, v32, u, pool+PW_1, W2, b2, decv, genv, barv16);
  k_gemm<1,1><<<dim3(128,4), dim3(256), 0, stream>>>(barv16, pool+PW_IH, b_ih, b_hh, xg, nullptr, 256, 1024);
  k_scan<0><<<dim3(8), dim3(1024), 0, stream>>>(pool+PW_HH, xg, h2);
  k_classify<<<dim3(256), dim3(256), 0, stream>>>(hist1 + (size_t)63*Bx*Hx, h2,
      pool+PC_1, C1b, pool+PC_2, C2b, pool+PC_O, Cob, out);
  k_copy<<<dim3(32), dim3(256), 0, stream>>>(sts, label, out);
}

// Round 4
// 667.342 us; speedup vs baseline: 1.8389x; 1.8389x over previous
//
#include <hip/hip_runtime.h>

#define DEV __device__ __forceinline__

typedef float f32x4 __attribute__((ext_vector_type(4)));
typedef short s16x8 __attribute__((ext_vector_type(8)));
typedef short s16x4 __attribute__((ext_vector_type(4)));

// ---------- scalar helpers ----------
DEV unsigned short f2bf(float f){
  unsigned int u = __float_as_uint(f);
  u += 0x7fffu + ((u>>16)&1u);
  return (unsigned short)(u>>16);
}
DEV float bf2f(unsigned short h){ return __uint_as_float(((unsigned int)h)<<16); }

#if __has_builtin(__builtin_amdgcn_rcpf)
DEV float frcp_(float x){ return __builtin_amdgcn_rcpf(x); }
#else
DEV float frcp_(float x){ return 1.f/x; }
#endif
#if __has_builtin(__builtin_amdgcn_exp2f)
DEV float fexp2_(float x){ return __builtin_amdgcn_exp2f(x); }
#else
DEV float fexp2_(float x){ return exp2f(x); }
#endif

DEV float sigm(float x){ return frcp_(1.f + fexp2_(-1.4426950408889634f*x)); }
DEV float tanh_(float x){
  x = fminf(x, 30.f);                       // overflow guard
  float e = fexp2_(2.8853900817779268f*x);
  return (e-1.f)*frcp_(e+1.f);
}

// branchless f32 -> OCP e4m3fn (RNE, saturating; subnormal inputs flush to 0)
DEV unsigned char f2e4m3(float x){
  unsigned int u = __float_as_uint(x);
  unsigned int s = (u>>24)&0x80u;
  unsigned int mag = u & 0x7fffffffu;
  if (mag > 0x43E00000u) mag = 0x43E00000u;          // clamp to 448
  mag += 0x000FFFFFu + ((mag>>20)&1u);               // RNE to 3-bit mantissa
  int e = (int)(mag>>23) - 120;                      // e4m3 biased exponent
  unsigned int m = (mag>>20)&7u;
  unsigned int r = (e<=0) ? 0u : (((unsigned)e<<3)|m);
  return (unsigned char)(s|r);
}

DEV f32x4 mfma_bf16(s16x8 a, s16x8 b, f32x4 c){
  return __builtin_amdgcn_mfma_f32_16x16x32_bf16(a,b,c,0,0,0);
}
DEV f32x4 mfma_fp8(long a, long b, f32x4 c){
  return __builtin_amdgcn_mfma_f32_16x16x32_fp8_fp8(a,b,c,0,0,0);
}

// ---------- problem constants ----------
#define Bx 128
#define Vx 64
#define Sx 40
#define Dx 256
#define Hx 256

// d_out element offsets (f32)
#define OFF_OG   0
#define OFF_FAKE 256
#define OFF_DECV 512
#define OFF_GENV 2097664      // 512 + 128*64*256
#define OFF_STS  4194816      // OFF_GENV + 128*64*256
#define OFF_LBL  4203008      // OFF_STS + 8192

// bf16 weight-pool element offsets
#define PW_IH  0
#define PW_HH  262144
#define PW_HK  524288
#define PW_1   589824
#define PC_1   622592
#define PC_2   884736
#define PC_O   1409024
#define P_TOT  1410048

// ---------- K0: f32 weights -> bf16 pool + fp8 W_hh (x16) ----------
__global__ void k_cvtall(const float* __restrict__ W_ih, const float* __restrict__ Whh,
                         const float* __restrict__ Whk, const float* __restrict__ W1,
                         const float* __restrict__ C1W, const float* __restrict__ C2W,
                         const float* __restrict__ CoW, unsigned short* __restrict__ dst,
                         unsigned char* __restrict__ dst8){
  int i = blockIdx.x*256 + threadIdx.x;
  if (i < P_TOT){
    float v;
    if      (i < PW_HH) v = W_ih[i - PW_IH];
    else if (i < PW_HK) v = Whh [i - PW_HH];
    else if (i < PW_1 ) v = Whk [i - PW_HK];
    else if (i < PC_1 ) v = W1  [i - PW_1 ];
    else if (i < PC_2 ) v = C1W [i - PC_1 ];
    else if (i < PC_O ) v = C2W [i - PC_2 ];
    else                v = CoW [i - PC_O ];
    dst[i] = f2bf(v);
  } else if (i < P_TOT + 262144){
    dst8[i - P_TOT] = f2e4m3(16.f*Whh[i - P_TOT]);
  }
}

// ---------- K1: v = sum_s relu(emb[idx]) ; dual-store; Dec/Gen row 0 ----------
__global__ void k_embed(const int* __restrict__ seqs, const float* __restrict__ emb,
                        float* __restrict__ v32, unsigned short* __restrict__ v16,
                        float* __restrict__ decv, float* __restrict__ genv,
                        unsigned short* __restrict__ barv16){
  int bt = blockIdx.x;          // b*64 + t
  int d = threadIdx.x;
  const int* sp = seqs + (size_t)bt*Sx;
  float acc = 0.f;
  #pragma unroll 4
  for (int s=0;s<Sx;s++){
    int id = sp[s];
    acc += fmaxf(emb[(size_t)id*Dx + d], 0.f);
  }
  size_t o = (size_t)bt*Dx + d;
  v32[o] = acc;
  v16[o] = f2bf(acc);
  if ((bt & 63) == 0){          // t == 0: bar_v row 0 = v[:,0,:]
    decv[o] = acc; genv[o] = acc; barv16[o] = f2bf(acc);
  }
}

// ---------- generic MFMA GEMM: C = scale*(A[M,K]*Bw[N,K]^T + bias1 + bias2) ----------
// MODE_A: 0 = row-major rows m (pitch K); 1 = v-layout [b][t][d], m = t*128+b
// MODE_C: 0 = row-major [m][n] bf16 (pitch Ntot); 1 = xg layout [t][g][n][16b] bf16
template<int MODE_A, int MODE_C>
__global__ void k_gemm(const unsigned short* __restrict__ A, const unsigned short* __restrict__ Bw,
                       const float* __restrict__ bias1, const float* __restrict__ bias2,
                       unsigned short* __restrict__ C, int K, int Ntot, float scale){
  int tid = threadIdx.x, w = tid>>6, l = tid&63, lm = l&15, q = l>>4;
  int m0 = blockIdx.x*64;
  int n0 = blockIdx.y*256 + w*64;
  f32x4 acc[4][4];
  #pragma unroll
  for (int nt=0;nt<4;nt++){
    int n = n0 + nt*16 + lm;
    float bz = bias1 ? bias1[n] : 0.f;
    if (bias2) bz += bias2[n];
    #pragma unroll
    for (int mt=0;mt<4;mt++) acc[mt][nt] = (f32x4){bz,bz,bz,bz};
  }
  const s16x8* Arow[4];
  #pragma unroll
  for (int mt=0;mt<4;mt++){
    int m = m0 + mt*16 + lm;
    size_t off = (MODE_A==0) ? (size_t)m*K : ((size_t)(m&127)*Vx + (m>>7))*(size_t)K;
    Arow[mt] = (const s16x8*)(A + off);
  }
  int kkn = K/32;
  for (int kk=0; kk<kkn; kk++){
    s16x8 bfr[4];
    #pragma unroll
    for (int nt=0;nt<4;nt++){
      int n = n0 + nt*16 + lm;
      bfr[nt] = *(const s16x8*)(Bw + (size_t)n*K + kk*32 + q*8);
    }
    #pragma unroll
    for (int mt=0;mt<4;mt++){
      s16x8 afr = Arow[mt][kk*4 + q];
      #pragma unroll
      for (int nt=0;nt<4;nt++)
        acc[mt][nt] = mfma_bf16(afr, bfr[nt], acc[mt][nt]);
    }
  }
  #pragma unroll
  for (int mt=0;mt<4;mt++){
    int mbase = m0 + mt*16 + q*4;
    #pragma unroll
    for (int nt=0;nt<4;nt++){
      int n = n0 + nt*16 + lm;
      if (MODE_C==0){
        #pragma unroll
        for (int r=0;r<4;r++)
          C[(size_t)(mbase+r)*Ntot + n] = f2bf(scale*acc[mt][nt][r]);
      } else {
        int tt = mbase>>7, bb = mbase&127;
        int gg = bb>>4, b4 = bb&15;          // b4 == q*4
        s16x4 sv;
        #pragma unroll
        for (int r=0;r<4;r++) sv[r] = (short)f2bf(scale*acc[mt][nt][r]);
        *(s16x4*)(C + (((size_t)tt*8 + gg)*1024 + n)*16 + b4) = sv;
      }
    }
  }
}

// ---------- K3/K7: LSTM scan, fp8 MFMA (W_hh x16 in regs, h x16 in LDS) ----------
// xg pre-scaled x256 bf16 [t][g][n][16b]; hist: exact-h bf16
#define HPB 264   // LDS row pitch in BYTES: 66 dwords, 66%32==2 -> near-conflict-free b64
template<int STORE_ALL>
__global__ __launch_bounds__(1024) void k_scan(const unsigned char* __restrict__ W8,
        const unsigned short* __restrict__ xg, unsigned short* __restrict__ hist){
  __shared__ __align__(16) unsigned char hl[2][16*HPB];
  int tid = threadIdx.x;
  int g = blockIdx.x;                        // batch group: b in [16g, 16g+16)
  int w = tid>>6, l = tid&63, lm = l&15, q = l>>4;
  int j = w*16 + lm;                         // hidden index owned by this lane
  for (int i=tid;i<2*16*HPB;i+=1024) ((unsigned char*)hl)[i] = 0;
  long Bf[4][8];                             // fp8 W_hh fragments: 64 VGPRs
  #pragma unroll
  for (int qq=0;qq<4;qq++){
    int n = qq*256 + j;
    #pragma unroll
    for (int kk=0;kk<8;kk++)
      Bf[qq][kk] = *(const long*)(W8 + (size_t)n*256 + kk*32 + q*8);
  }
  float cst[4] = {0.f,0.f,0.f,0.f};
  const unsigned short* xgb = xg + (size_t)g*16384 + q*4;    // [t][g][n][16]
  s16x4 xc[4], xn[4];
  #pragma unroll
  for (int qq=0;qq<4;qq++) xc[qq] = *(const s16x4*)(xgb + (qq*256+j)*16);
  __syncthreads();
  const float K1 = 1.4426950408889634f/256.f;   // fold /256 descale into exp2 consts
  #pragma unroll 1
  for (int t=0;t<Vx;t++){
    if (t < Vx-1){
      #pragma unroll
      for (int qq=0;qq<4;qq++)
        xn[qq] = *(const s16x4*)(xgb + (size_t)(t+1)*131072 + (qq*256+j)*16);
    }
    f32x4 acc[4];
    #pragma unroll
    for (int qq=0;qq<4;qq++){
      #pragma unroll
      for (int r=0;r<4;r++) acc[qq][r] = bf2f((unsigned short)xc[qq][r]);
    }
    const unsigned char* hb = hl[t&1];
    #pragma unroll
    for (int kk=0;kk<8;kk++){
      long af = *(const long*)(hb + lm*HPB + kk*32 + q*8);
      acc[0] = mfma_fp8(af, Bf[0][kk], acc[0]);
      acc[1] = mfma_fp8(af, Bf[1][kk], acc[1]);
      acc[2] = mfma_fp8(af, Bf[2][kk], acc[2]);
      acc[3] = mfma_fp8(af, Bf[3][kk], acc[3]);
    }
    unsigned char* hn = hl[(t+1)&1];
    #pragma unroll
    for (int r=0;r<4;r++){
      float iv = frcp_(1.f + fexp2_(-K1*acc[0][r]));
      float fv = frcp_(1.f + fexp2_(-K1*acc[1][r]));
      float eg = fexp2_(2.f*K1*acc[2][r]);
      float gv = (eg-1.f)*frcp_(eg+1.f);
      float ov = frcp_(1.f + fexp2_(-K1*acc[3][r]));
      float cv = fv*cst[r] + iv*gv;
      cst[r] = cv;
      float ec = fexp2_(2.8853900817779268f*fminf(cv,30.f));
      float hv = ov*(ec-1.f)*frcp_(ec+1.f);
      hn[(q*4+r)*HPB + j] = f2e4m3(16.f*hv);
      if (STORE_ALL)
        hist[((size_t)t*Bx + g*16 + q*4 + r)*Hx + j] = f2bf(hv);
      else if (t==Vx-1)
        hist[((size_t)(g*16 + q*4 + r))*Hx + j] = f2bf(hv);
    }
    #pragma unroll
    for (int qq=0;qq<4;qq++) xc[qq] = xn[qq];
    __syncthreads();
  }
}

// ---------- K5a: u[b][n] = e_k[b] @ W1[:, :256]^T + b1 (f32) ----------
__global__ void k_u(const float* __restrict__ v32, const float* __restrict__ W1,
                    const float* __restrict__ b1, float* __restrict__ u){
  int b = blockIdx.x, n = threadIdx.x;   // 128 x 64
  const f32x4* vr = (const f32x4*)(v32 + (size_t)b*Vx*Dx);   // v[b][0][:]
  const f32x4* wr = (const f32x4*)(W1 + (size_t)n*512);
  float a = b1[n];
  for (int kk=0;kk<64;kk++){
    f32x4 x = vr[kk], ww = wr[kk];
    a += x[0]*ww[0] + x[1]*ww[1] + x[2]*ww[2] + x[3]*ww[3];
  }
  u[(size_t)b*64 + n] = a;
}

// ---------- K5b: attention + bar_v -> Dec_V/Gen_V rows t'=1..63 ----------
__global__ void k_attn(const unsigned short* __restrict__ wh16,
                       const float* __restrict__ v32, const float* __restrict__ u,
                       const unsigned short* __restrict__ W116, const float* __restrict__ W2,
                       const float* __restrict__ b2,
                       float* __restrict__ decv, float* __restrict__ genv,
                       unsigned short* __restrict__ barv16){
  int tid = threadIdx.x, w = tid>>6, l = tid&63, lm = l&15, q = l>>4;
  int mt = blockIdx.x*4 + w;            // 504 M-tiles of 16 rows, rows m = t'*128 + b
  int m0 = mt*16;
  f32x4 acc[4];
  #pragma unroll
  for (int nt=0;nt<4;nt++){
    int n = nt*16 + lm;
    f32x4 a;
    #pragma unroll
    for (int r=0;r<4;r++) a[r] = u[(size_t)((m0 + q*4 + r)&127)*64 + n];
    acc[nt] = a;
  }
  const s16x8* Arow = (const s16x8*)(wh16 + (size_t)(m0+lm)*Dx);
  #pragma unroll
  for (int kk=0;kk<8;kk++){
    s16x8 af = Arow[kk*4 + q];
    #pragma unroll
    for (int nt=0;nt<4;nt++){
      int n = nt*16 + lm;
      s16x8 bf = *(const s16x8*)(W116 + (size_t)n*512 + 256 + kk*32 + q*8);
      acc[nt] = mfma_bf16(af, bf, acc[nt]);
    }
  }
  float p0a[4] = {0,0,0,0}, p1a[4] = {0,0,0,0};
  #pragma unroll
  for (int nt=0;nt<4;nt++){
    int n = nt*16 + lm;
    float w2a = W2[n], w2b = W2[64+n];
    #pragma unroll
    for (int r=0;r<4;r++){
      float z = tanh_(acc[nt][r]);
      p0a[r] += z*w2a; p1a[r] += z*w2b;
    }
  }
  #pragma unroll
  for (int s=1;s<16;s<<=1){
    #pragma unroll
    for (int r=0;r<4;r++){ p0a[r] += __shfl_xor(p0a[r], s, 16); p1a[r] += __shfl_xor(p1a[r], s, 16); }
  }
  float bb0 = b2[0], bb1 = b2[1];
  int t = m0>>7;                         // t' (uniform per wave)
  int d0 = lm*16;
  #pragma unroll
  for (int r=0;r<4;r++){
    int m = m0 + q*4 + r; int b = m&127;
    float a0 = p0a[r]+bb0, a1 = p1a[r]+bb1;
    float al0 = frcp_(1.f + fexp2_(1.4426950408889634f*(a1-a0)));  // softmax over {a0,a1}
    float al1 = 1.f - al0;
    const f32x4* ek = (const f32x4*)(v32 + (size_t)b*Vx*Dx + d0);
    const unsigned short* whr = wh16 + (size_t)m*Dx + d0;
    size_t ob = ((size_t)b*Vx + (t+1))*Dx + d0;
    #pragma unroll
    for (int c=0;c<4;c++){
      f32x4 e = ek[c], o;
      s16x4 o16;
      #pragma unroll
      for (int jj=0;jj<4;jj++){
        o[jj] = al0*e[jj] + al1*bf2f(whr[c*4+jj]);
        o16[jj] = (short)f2bf(o[jj]);
      }
      *(f32x4*)(decv + ob + c*4) = o;
      *(f32x4*)(genv + ob + c*4) = o;
      *(s16x4*)(barv16 + ob + c*4) = o16;
    }
  }
}

// ---------- K8: classifier heads on h1[t=63] and h2 ----------
__global__ void k_classify(const unsigned short* __restrict__ h1, const unsigned short* __restrict__ h2,
    const unsigned short* __restrict__ C1W16, const float* __restrict__ C1b,
    const unsigned short* __restrict__ C2W16, const float* __restrict__ C2b,
    const unsigned short* __restrict__ CoW16, const float* __restrict__ Cob,
    float* __restrict__ out){
  int blk = blockIdx.x;                // 0..255
  int b = blk & 127; bool fake = blk >= 128;
  const unsigned short* X = fake ? (h2 + (size_t)b*Hx) : (h1 + (size_t)b*Hx);
  __shared__ float xs[256]; __shared__ float y1[1024]; __shared__ float y2[512];
  __shared__ float r0[256], r1[256];
  int tid = threadIdx.x;
  xs[tid] = bf2f(X[tid]);
  __syncthreads();
  for (int n = tid; n < 1024; n += 256){
    const s16x8* wr = (const s16x8*)(C1W16 + (size_t)n*256);
    float a = C1b[n];
    for (int kk=0;kk<32;kk++){
      s16x8 ww = wr[kk];
      #pragma unroll
      for (int jj=0;jj<8;jj++) a += xs[kk*8+jj]*bf2f((unsigned short)ww[jj]);
    }
    y1[n] = fmaxf(a, 0.f);
  }
  __syncthreads();
  for (int n = tid; n < 512; n += 256){
    const s16x8* wr = (const s16x8*)(C2W16 + (size_t)n*1024);
    float a = C2b[n];
    for (int kk=0;kk<128;kk++){
      s16x8 ww = wr[kk];
      #pragma unroll
      for (int jj=0;jj<8;jj++) a += y1[kk*8+jj]*bf2f((unsigned short)ww[jj]);
    }
    y2[n] = fmaxf(a, 0.f);
  }
  __syncthreads();
  float p0 = 0.f, p1 = 0.f;
  for (int k = tid; k < 512; k += 256){
    float yv = y2[k];
    p0 += yv*bf2f(CoW16[k]); p1 += yv*bf2f(CoW16[512+k]);
  }
  r0[tid] = p0; r1[tid] = p1; __syncthreads();
  for (int s=128; s>0; s>>=1){
    if (tid < s){ r0[tid] += r0[tid+s]; r1[tid] += r1[tid+s]; }
    __syncthreads();
  }
  if (tid == 0){
    int base = (fake ? OFF_FAKE : OFF_OG) + b*2;
    out[base+0] = r0[0] + Cob[0];
    out[base+1] = r1[0] + Cob[1];
  }
}

// ---------- K9: passthrough outputs ----------
__global__ void k_copy(const float* __restrict__ sts, const int* __restrict__ label,
                       float* __restrict__ out){
  int i = blockIdx.x*256 + threadIdx.x;
  if (i < Bx*Vx) out[OFF_STS + i] = sts[i];
  if (i < Bx)    out[OFF_LBL + i] = (float)label[i];
}

// ---------- launch ----------
extern "C" void kernel_launch(void* const* d_in, const int* in_sizes, int n_in,
                              void* d_out, int out_size, void* d_ws, size_t ws_size,
                              hipStream_t stream) {
  const int*   seqs  = (const int*)d_in[0];
  const float* sts   = (const float*)d_in[3];
  const int*   label = (const int*)d_in[5];
  const float* emb   = (const float*)d_in[6];
  const float* W_ih  = (const float*)d_in[7];
  const float* W_hh  = (const float*)d_in[8];
  const float* b_ih  = (const float*)d_in[9];
  const float* b_hh  = (const float*)d_in[10];
  const float* Whk   = (const float*)d_in[11];
  const float* bhk   = (const float*)d_in[12];
  const float* W1    = (const float*)d_in[13];
  const float* b1    = (const float*)d_in[14];
  const float* W2    = (const float*)d_in[15];
  const float* b2    = (const float*)d_in[16];
  const float* C1b   = (const float*)d_in[18];
  const float* C2b   = (const float*)d_in[20];
  const float* Cob   = (const float*)d_in[22];
  float* out = (float*)d_out;

  char* ws = (char*)d_ws;
  unsigned short* v16    = (unsigned short*)(ws + 0);          //  4 MB [b][t][d] bf16
  unsigned short* xg     = (unsigned short*)(ws + (4<<20));    // 16 MB [t][g][n][16] bf16 (x256)
  unsigned short* hist1  = (unsigned short*)(ws + (20<<20));   //  4 MB [t][b][j] bf16
  unsigned short* wh16   = (unsigned short*)(ws + (24<<20));   //  4 MB [m][d] bf16
  unsigned short* barv16 = (unsigned short*)(ws + (28<<20));   //  4 MB [b][t][d] bf16
  float*          v32    = (float*)(ws + (32<<20));            //  8 MB [b][t][d] f32
  float*          u      = (float*)(ws + (40<<20));            // 32 KB [b][n] f32
  unsigned short* h2     = (unsigned short*)(ws + (40<<20) + (128<<10)); // 64 KB
  unsigned char*  whh8   = (unsigned char*)(ws + (40<<20) + (256<<10)); // 256 KB fp8 W_hh*16
  unsigned short* pool   = (unsigned short*)(ws + (41<<20));   // 2.82 MB bf16 weights

  float* decv = out + OFF_DECV;
  float* genv = out + OFF_GENV;

  k_cvtall<<<dim3(6532), dim3(256), 0, stream>>>(W_ih, W_hh, Whk, W1,
      (const float*)d_in[17], (const float*)d_in[19], (const float*)d_in[21], pool, whh8);
  k_embed<<<dim3(Bx*Vx), dim3(256), 0, stream>>>(seqs, emb, v32, v16, decv, genv, barv16);
  k_gemm<1,1><<<dim3(128,4), dim3(256), 0, stream>>>(v16, pool+PW_IH, b_ih, b_hh, xg, 256, 1024, 256.f);
  k_scan<1><<<dim3(8), dim3(1024), 0, stream>>>(whh8, xg, hist1);
  k_u<<<dim3(128), dim3(64), 0, stream>>>(v32, W1, b1, u);
  k_gemm<0,0><<<dim3(128,1), dim3(256), 0, stream>>>(hist1, pool+PW_HK, bhk, nullptr, wh16, 256, 256, 1.f);
  k_attn<<<dim3(126), dim3(256), 0, stream>>>(wh16, v32, u, pool+PW_1, W2, b2, decv, genv, barv16);
  k_gemm<1,1><<<dim3(128,4), dim3(256), 0, stream>>>(barv16, pool+PW_IH, b_ih, b_hh, xg, 256, 1024, 256.f);
  k_scan<0><<<dim3(8), dim3(1024), 0, stream>>>(whh8, xg, h2);
  k_classify<<<dim3(256), dim3(256), 0, stream>>>(hist1 + (size_t)63*Bx*Hx, h2,
      pool+PC_1, C1b, pool+PC_2, C2b, pool+PC_O, Cob, out);
  k_copy<<<dim3(32), dim3(256), 0, stream>>>(sts, label, out);
}

// Round 5
// 595.349 us; speedup vs baseline: 2.0613x; 1.1209x over previous
//
#include <hip/hip_runtime.h>

#define DEV __device__ __forceinline__

typedef float f32x4 __attribute__((ext_vector_type(4)));
typedef short s16x8 __attribute__((ext_vector_type(8)));
typedef short s16x4 __attribute__((ext_vector_type(4)));

// ---------- scalar helpers ----------
DEV unsigned short f2bf(float f){
  unsigned int u = __float_as_uint(f);
  u += 0x7fffu + ((u>>16)&1u);
  return (unsigned short)(u>>16);
}
DEV float bf2f(unsigned short h){ return __uint_as_float(((unsigned int)h)<<16); }

#if __has_builtin(__builtin_amdgcn_rcpf)
DEV float frcp_(float x){ return __builtin_amdgcn_rcpf(x); }
#else
DEV float frcp_(float x){ return 1.f/x; }
#endif
#if __has_builtin(__builtin_amdgcn_exp2f)
DEV float fexp2_(float x){ return __builtin_amdgcn_exp2f(x); }
#else
DEV float fexp2_(float x){ return exp2f(x); }
#endif

DEV float sigm(float x){ return frcp_(1.f + fexp2_(-1.4426950408889634f*x)); }
DEV float tanh_(float x){
  x = fminf(x, 30.f);                       // overflow guard
  float e = fexp2_(2.8853900817779268f*x);
  return (e-1.f)*frcp_(e+1.f);
}

// branchless f32 -> OCP e4m3fn (fallback when no HW cvt)
DEV unsigned char f2e4m3(float x){
  unsigned int u = __float_as_uint(x);
  unsigned int s = (u>>24)&0x80u;
  unsigned int mag = u & 0x7fffffffu;
  if (mag > 0x43E00000u) mag = 0x43E00000u;          // clamp to 448
  mag += 0x000FFFFFu + ((mag>>20)&1u);               // RNE to 3-bit mantissa
  int e = (int)(mag>>23) - 120;                      // e4m3 biased exponent
  unsigned int m = (mag>>20)&7u;
  unsigned int r = (e<=0) ? 0u : (((unsigned)e<<3)|m);
  return (unsigned char)(s|r);
}

DEV f32x4 mfma_bf16(s16x8 a, s16x8 b, f32x4 c){
  return __builtin_amdgcn_mfma_f32_16x16x32_bf16(a,b,c,0,0,0);
}
DEV f32x4 mfma_fp8(long a, long b, f32x4 c){
  return __builtin_amdgcn_mfma_f32_16x16x32_fp8_fp8(a,b,c,0,0,0);
}

// LDS-only barrier: do NOT drain vmcnt (global prefetch/stores stay in flight).
DEV void lds_barrier(){
  asm volatile("s_waitcnt lgkmcnt(0)\n\ts_barrier" ::: "memory");
}

// ---------- problem constants ----------
#define Bx 128
#define Vx 64
#define Sx 40
#define Dx 256
#define Hx 256

// d_out element offsets (f32)
#define OFF_OG   0
#define OFF_FAKE 256
#define OFF_DECV 512
#define OFF_GENV 2097664      // 512 + 128*64*256
#define OFF_STS  4194816      // OFF_GENV + 128*64*256
#define OFF_LBL  4203008      // OFF_STS + 8192

// bf16 weight-pool element offsets
#define PW_IH  0
#define PW_HH  262144
#define PW_HK  524288
#define PW_1   589824
#define PC_1   622592
#define PC_2   884736
#define PC_O   1409024
#define P_TOT  1410048

// ---------- K0: f32 weights -> bf16 pool + fp8 W_hh (x16) ----------
__global__ void k_cvtall(const float* __restrict__ W_ih, const float* __restrict__ Whh,
                         const float* __restrict__ Whk, const float* __restrict__ W1,
                         const float* __restrict__ C1W, const float* __restrict__ C2W,
                         const float* __restrict__ CoW, unsigned short* __restrict__ dst,
                         unsigned char* __restrict__ dst8){
  int i = blockIdx.x*256 + threadIdx.x;
  if (i < P_TOT){
    float v;
    if      (i < PW_HH) v = W_ih[i - PW_IH];
    else if (i < PW_HK) v = Whh [i - PW_HH];
    else if (i < PW_1 ) v = Whk [i - PW_HK];
    else if (i < PC_1 ) v = W1  [i - PW_1 ];
    else if (i < PC_2 ) v = C1W [i - PC_1 ];
    else if (i < PC_O ) v = C2W [i - PC_2 ];
    else                v = CoW [i - PC_O ];
    dst[i] = f2bf(v);
  } else if (i < P_TOT + 262144){
    dst8[i - P_TOT] = f2e4m3(16.f*Whh[i - P_TOT]);
  }
}

// ---------- K1: v = sum_s relu(emb[idx]) ; dual-store; Dec/Gen row 0 ----------
__global__ void k_embed(const int* __restrict__ seqs, const float* __restrict__ emb,
                        float* __restrict__ v32, unsigned short* __restrict__ v16,
                        float* __restrict__ decv, float* __restrict__ genv,
                        unsigned short* __restrict__ barv16){
  int bt = blockIdx.x;          // b*64 + t
  int d = threadIdx.x;
  const int* sp = seqs + (size_t)bt*Sx;
  float acc = 0.f;
  #pragma unroll 4
  for (int s=0;s<Sx;s++){
    int id = sp[s];
    acc += fmaxf(emb[(size_t)id*Dx + d], 0.f);
  }
  size_t o = (size_t)bt*Dx + d;
  v32[o] = acc;
  v16[o] = f2bf(acc);
  if ((bt & 63) == 0){          // t == 0: bar_v row 0 = v[:,0,:]
    decv[o] = acc; genv[o] = acc; barv16[o] = f2bf(acc);
  }
}

// ---------- generic MFMA GEMM: C = act(scale*(A[M,K]*Bw[N,K]^T + bias1 + bias2)) ----------
// MODE_A: 0 = row-major rows m (pitch K); 1 = v-layout [b][t][d], m = t*128+b
// MODE_C: 0 = row-major [m][n] bf16 (pitch Ntot); 1 = xg layout [t][g][n][16b] bf16
// RELU:   apply fmax(0) in epilogue
template<int MODE_A, int MODE_C, int RELU>
__global__ void k_gemm(const unsigned short* __restrict__ A, const unsigned short* __restrict__ Bw,
                       const float* __restrict__ bias1, const float* __restrict__ bias2,
                       unsigned short* __restrict__ C, int K, int Ntot, float scale){
  int tid = threadIdx.x, w = tid>>6, l = tid&63, lm = l&15, q = l>>4;
  int m0 = blockIdx.x*64;
  int n0 = blockIdx.y*256 + w*64;
  f32x4 acc[4][4];
  #pragma unroll
  for (int nt=0;nt<4;nt++){
    int n = n0 + nt*16 + lm;
    float bz = bias1 ? bias1[n] : 0.f;
    if (bias2) bz += bias2[n];
    #pragma unroll
    for (int mt=0;mt<4;mt++) acc[mt][nt] = (f32x4){bz,bz,bz,bz};
  }
  const s16x8* Arow[4];
  #pragma unroll
  for (int mt=0;mt<4;mt++){
    int m = m0 + mt*16 + lm;
    size_t off = (MODE_A==0) ? (size_t)m*K : ((size_t)(m&127)*Vx + (m>>7))*(size_t)K;
    Arow[mt] = (const s16x8*)(A + off);
  }
  int kkn = K/32;
  for (int kk=0; kk<kkn; kk++){
    s16x8 bfr[4];
    #pragma unroll
    for (int nt=0;nt<4;nt++){
      int n = n0 + nt*16 + lm;
      bfr[nt] = *(const s16x8*)(Bw + (size_t)n*K + kk*32 + q*8);
    }
    #pragma unroll
    for (int mt=0;mt<4;mt++){
      s16x8 afr = Arow[mt][kk*4 + q];
      #pragma unroll
      for (int nt=0;nt<4;nt++)
        acc[mt][nt] = mfma_bf16(afr, bfr[nt], acc[mt][nt]);
    }
  }
  #pragma unroll
  for (int mt=0;mt<4;mt++){
    int mbase = m0 + mt*16 + q*4;
    #pragma unroll
    for (int nt=0;nt<4;nt++){
      int n = n0 + nt*16 + lm;
      if (MODE_C==0){
        #pragma unroll
        for (int r=0;r<4;r++){
          float val = scale*acc[mt][nt][r];
          if (RELU) val = fmaxf(val, 0.f);
          C[(size_t)(mbase+r)*Ntot + n] = f2bf(val);
        }
      } else {
        int tt = mbase>>7, bb = mbase&127;
        int gg = bb>>4, b4 = bb&15;          // b4 == q*4
        s16x4 sv;
        #pragma unroll
        for (int r=0;r<4;r++){
          float val = scale*acc[mt][nt][r];
          if (RELU) val = fmaxf(val, 0.f);
          sv[r] = (short)f2bf(val);
        }
        *(s16x4*)(C + (((size_t)tt*8 + gg)*1024 + n)*16 + b4) = sv;
      }
    }
  }
}

// ---------- K3/K7: LSTM scan, fp8 MFMA (W_hh x16 in regs, h x16 in LDS) ----------
// xg pre-scaled x256 bf16 [t][g][n][16b]; hist: exact-h bf16
#define HPB 264   // LDS row pitch in BYTES
template<int STORE_ALL>
__global__ __launch_bounds__(1024) void k_scan(const unsigned char* __restrict__ W8,
        const unsigned short* __restrict__ xg, unsigned short* __restrict__ hist){
  __shared__ __align__(16) unsigned char hl[2][16*HPB];
  int tid = threadIdx.x;
  int g = blockIdx.x;                        // batch group: b in [16g, 16g+16)
  int w = tid>>6, l = tid&63, lm = l&15, q = l>>4;
  int j = w*16 + lm;                         // hidden index owned by this lane
  for (int i=tid;i<2*16*HPB;i+=1024) ((unsigned char*)hl)[i] = 0;
  long Bf[4][8];                             // fp8 W_hh fragments
  #pragma unroll
  for (int qq=0;qq<4;qq++){
    int n = qq*256 + j;
    #pragma unroll
    for (int kk=0;kk<8;kk++)
      Bf[qq][kk] = *(const long*)(W8 + (size_t)n*256 + kk*32 + q*8);
  }
  float cst[4] = {0.f,0.f,0.f,0.f};
  const unsigned short* xgb = xg + (size_t)g*16384 + q*4;    // [t][g][n][16]
  s16x4 xc[4], xn[4];
  #pragma unroll
  for (int qq=0;qq<4;qq++) xc[qq] = *(const s16x4*)(xgb + (qq*256+j)*16);
  __syncthreads();
  const float K1 = 1.4426950408889634f/256.f;   // fold /256 descale into exp2 consts
  #pragma unroll 1
  for (int t=0;t<Vx;t++){
    if (t < Vx-1){
      #pragma unroll
      for (int qq=0;qq<4;qq++)
        xn[qq] = *(const s16x4*)(xgb + (size_t)(t+1)*131072 + (qq*256+j)*16);
    }
    f32x4 acc[4];
    #pragma unroll
    for (int qq=0;qq<4;qq++){
      #pragma unroll
      for (int r=0;r<4;r++) acc[qq][r] = bf2f((unsigned short)xc[qq][r]);
    }
    const unsigned char* hb = hl[t&1];
    #pragma unroll
    for (int kk=0;kk<8;kk++){
      long af = *(const long*)(hb + lm*HPB + kk*32 + q*8);
      acc[0] = mfma_fp8(af, Bf[0][kk], acc[0]);
      acc[1] = mfma_fp8(af, Bf[1][kk], acc[1]);
      acc[2] = mfma_fp8(af, Bf[2][kk], acc[2]);
      acc[3] = mfma_fp8(af, Bf[3][kk], acc[3]);
    }
    unsigned char* hn = hl[(t+1)&1];
    float hv16[4];
    #pragma unroll
    for (int r=0;r<4;r++){
      float iv = frcp_(1.f + fexp2_(-K1*acc[0][r]));
      float fv = frcp_(1.f + fexp2_(-K1*acc[1][r]));
      float eg = fexp2_(2.f*K1*acc[2][r]);
      float gv = (eg-1.f)*frcp_(eg+1.f);
      float ov = frcp_(1.f + fexp2_(-K1*acc[3][r]));
      float cv = fv*cst[r] + iv*gv;
      cst[r] = cv;
      float ec = fexp2_(2.8853900817779268f*fminf(cv,30.f));
      float hv = ov*(ec-1.f)*frcp_(ec+1.f);
      hv16[r] = 16.f*hv;
      if (STORE_ALL)
        hist[((size_t)t*Bx + g*16 + q*4 + r)*Hx + j] = f2bf(hv);
      else if (t==Vx-1)
        hist[((size_t)(g*16 + q*4 + r))*Hx + j] = f2bf(hv);
    }
#if __has_builtin(__builtin_amdgcn_cvt_pk_fp8_f32)
    int p01 = __builtin_amdgcn_cvt_pk_fp8_f32(hv16[0], hv16[1], 0, false);
    int p23 = __builtin_amdgcn_cvt_pk_fp8_f32(hv16[2], hv16[3], 0, false);
    hn[(q*4+0)*HPB + j] = (unsigned char)p01;
    hn[(q*4+1)*HPB + j] = (unsigned char)(p01>>8);
    hn[(q*4+2)*HPB + j] = (unsigned char)p23;
    hn[(q*4+3)*HPB + j] = (unsigned char)(p23>>8);
#else
    #pragma unroll
    for (int r=0;r<4;r++) hn[(q*4+r)*HPB + j] = f2e4m3(hv16[r]);
#endif
    #pragma unroll
    for (int qq=0;qq<4;qq++) xc[qq] = xn[qq];
    lds_barrier();
  }
}

// ---------- K5a: u[b][n] = e_k[b] @ W1[:, :256]^T + b1 (f32) ----------
__global__ void k_u(const float* __restrict__ v32, const float* __restrict__ W1,
                    const float* __restrict__ b1, float* __restrict__ u){
  int b = blockIdx.x, n = threadIdx.x;   // 128 x 64
  const f32x4* vr = (const f32x4*)(v32 + (size_t)b*Vx*Dx);   // v[b][0][:]
  const f32x4* wr = (const f32x4*)(W1 + (size_t)n*512);
  float a = b1[n];
  for (int kk=0;kk<64;kk++){
    f32x4 x = vr[kk], ww = wr[kk];
    a += x[0]*ww[0] + x[1]*ww[1] + x[2]*ww[2] + x[3]*ww[3];
  }
  u[(size_t)b*64 + n] = a;
}

// ---------- K5b: attention + bar_v -> Dec_V/Gen_V rows t'=1..63 ----------
__global__ void k_attn(const unsigned short* __restrict__ wh16,
                       const float* __restrict__ v32, const float* __restrict__ u,
                       const unsigned short* __restrict__ W116, const float* __restrict__ W2,
                       const float* __restrict__ b2,
                       float* __restrict__ decv, float* __restrict__ genv,
                       unsigned short* __restrict__ barv16){
  int tid = threadIdx.x, w = tid>>6, l = tid&63, lm = l&15, q = l>>4;
  int mt = blockIdx.x*4 + w;            // 504 M-tiles of 16 rows, rows m = t'*128 + b
  int m0 = mt*16;
  f32x4 acc[4];
  #pragma unroll
  for (int nt=0;nt<4;nt++){
    int n = nt*16 + lm;
    f32x4 a;
    #pragma unroll
    for (int r=0;r<4;r++) a[r] = u[(size_t)((m0 + q*4 + r)&127)*64 + n];
    acc[nt] = a;
  }
  const s16x8* Arow = (const s16x8*)(wh16 + (size_t)(m0+lm)*Dx);
  #pragma unroll
  for (int kk=0;kk<8;kk++){
    s16x8 af = Arow[kk*4 + q];
    #pragma unroll
    for (int nt=0;nt<4;nt++){
      int n = nt*16 + lm;
      s16x8 bf = *(const s16x8*)(W116 + (size_t)n*512 + 256 + kk*32 + q*8);
      acc[nt] = mfma_bf16(af, bf, acc[nt]);
    }
  }
  float p0a[4] = {0,0,0,0}, p1a[4] = {0,0,0,0};
  #pragma unroll
  for (int nt=0;nt<4;nt++){
    int n = nt*16 + lm;
    float w2a = W2[n], w2b = W2[64+n];
    #pragma unroll
    for (int r=0;r<4;r++){
      float z = tanh_(acc[nt][r]);
      p0a[r] += z*w2a; p1a[r] += z*w2b;
    }
  }
  #pragma unroll
  for (int s=1;s<16;s<<=1){
    #pragma unroll
    for (int r=0;r<4;r++){ p0a[r] += __shfl_xor(p0a[r], s, 16); p1a[r] += __shfl_xor(p1a[r], s, 16); }
  }
  float bb0 = b2[0], bb1 = b2[1];
  int t = m0>>7;                         // t' (uniform per wave)
  int d0 = lm*16;
  #pragma unroll
  for (int r=0;r<4;r++){
    int m = m0 + q*4 + r; int b = m&127;
    float a0 = p0a[r]+bb0, a1 = p1a[r]+bb1;
    float al0 = frcp_(1.f + fexp2_(1.4426950408889634f*(a1-a0)));  // softmax over {a0,a1}
    float al1 = 1.f - al0;
    const f32x4* ek = (const f32x4*)(v32 + (size_t)b*Vx*Dx + d0);
    const unsigned short* whr = wh16 + (size_t)m*Dx + d0;
    size_t ob = ((size_t)b*Vx + (t+1))*Dx + d0;
    #pragma unroll
    for (int c=0;c<4;c++){
      f32x4 e = ek[c], o;
      s16x4 o16;
      #pragma unroll
      for (int jj=0;jj<4;jj++){
        o[jj] = al0*e[jj] + al1*bf2f(whr[c*4+jj]);
        o16[jj] = (short)f2bf(o[jj]);
      }
      *(f32x4*)(decv + ob + c*4) = o;
      *(f32x4*)(genv + ob + c*4) = o;
      *(s16x4*)(barv16 + ob + c*4) = o16;
    }
  }
}

// ---------- K8c: final logits: out = y2 @ CoW^T + Cob  (M=256, K=512, N=2) ----------
__global__ void k_out(const unsigned short* __restrict__ y2, const unsigned short* __restrict__ CoW16,
                      const float* __restrict__ Cob, float* __restrict__ out){
  int tid = blockIdx.x*256 + threadIdx.x;   // 512 threads total
  int m = tid>>1, n = tid&1;
  const s16x8* yr = (const s16x8*)(y2 + (size_t)m*512);
  const s16x8* wr = (const s16x8*)(CoW16 + (size_t)n*512);
  float a = Cob[n];
  for (int kk=0;kk<64;kk++){
    s16x8 yv = yr[kk], ww = wr[kk];
    #pragma unroll
    for (int jj=0;jj<8;jj++) a += bf2f((unsigned short)yv[jj])*bf2f((unsigned short)ww[jj]);
  }
  int base = (m < 128) ? (OFF_OG + m*2) : (OFF_FAKE + (m-128)*2);
  out[base + n] = a;
}

// ---------- K9: passthrough outputs ----------
__global__ void k_copy(const float* __restrict__ sts, const int* __restrict__ label,
                       float* __restrict__ out){
  int i = blockIdx.x*256 + threadIdx.x;
  if (i < Bx*Vx) out[OFF_STS + i] = sts[i];
  if (i < Bx)    out[OFF_LBL + i] = (float)label[i];
}

// ---------- launch ----------
extern "C" void kernel_launch(void* const* d_in, const int* in_sizes, int n_in,
                              void* d_out, int out_size, void* d_ws, size_t ws_size,
                              hipStream_t stream) {
  const int*   seqs  = (const int*)d_in[0];
  const float* sts   = (const float*)d_in[3];
  const int*   label = (const int*)d_in[5];
  const float* emb   = (const float*)d_in[6];
  const float* W_ih  = (const float*)d_in[7];
  const float* W_hh  = (const float*)d_in[8];
  const float* b_ih  = (const float*)d_in[9];
  const float* b_hh  = (const float*)d_in[10];
  const float* Whk   = (const float*)d_in[11];
  const float* bhk   = (const float*)d_in[12];
  const float* W1    = (const float*)d_in[13];
  const float* b1    = (const float*)d_in[14];
  const float* W2    = (const float*)d_in[15];
  const float* b2    = (const float*)d_in[16];
  const float* C1b   = (const float*)d_in[18];
  const float* C2b   = (const float*)d_in[20];
  const float* Cob   = (const float*)d_in[22];
  float* out = (float*)d_out;

  char* ws = (char*)d_ws;
  unsigned short* v16    = (unsigned short*)(ws + 0);           //  4 MiB [b][t][d] bf16
  unsigned short* xg     = (unsigned short*)(ws + (4<<20));     // 16 MiB [t][g][n][16] bf16 (x256)
  unsigned short* hist1  = (unsigned short*)(ws + (20<<20));    //  4 MiB [t][b][j] + 64 KiB h2
  unsigned short* wh16   = (unsigned short*)(ws + (25<<20));    //  3.94 MiB [m][d] bf16
  unsigned short* barv16 = (unsigned short*)(ws + (29<<20));    //  4 MiB [b][t][d] bf16
  float*          v32    = (float*)(ws + (33<<20));             //  8 MiB [b][t][d] f32
  float*          u      = (float*)(ws + (41<<20));             // 32 KiB [b][n] f32
  unsigned char*  whh8   = (unsigned char*)(ws + (41<<20) + (512<<10)); // 256 KiB fp8 W_hh*16
  unsigned short* pool   = (unsigned short*)(ws + (42<<20));    // 2.82 MiB bf16 weights
  unsigned short* y1     = (unsigned short*)(ws + (45<<20));    // 512 KiB [256][1024] bf16
  unsigned short* y2     = (unsigned short*)(ws + (45<<20) + (512<<10)); // 256 KiB [256][512]

  unsigned short* h2 = hist1 + (size_t)Vx*Bx*Hx;          // X rows 128..255
  unsigned short* X  = hist1 + (size_t)(Vx-1)*Bx*Hx;      // [256][256]: h1[63] ; h2

  float* decv = out + OFF_DECV;
  float* genv = out + OFF_GENV;

  k_cvtall<<<dim3(6532), dim3(256), 0, stream>>>(W_ih, W_hh, Whk, W1,
      (const float*)d_in[17], (const float*)d_in[19], (const float*)d_in[21], pool, whh8);
  k_embed<<<dim3(Bx*Vx), dim3(256), 0, stream>>>(seqs, emb, v32, v16, decv, genv, barv16);
  k_gemm<1,1,0><<<dim3(128,4), dim3(256), 0, stream>>>(v16, pool+PW_IH, b_ih, b_hh, xg, 256, 1024, 256.f);
  k_scan<1><<<dim3(8), dim3(1024), 0, stream>>>(whh8, xg, hist1);
  k_u<<<dim3(128), dim3(64), 0, stream>>>(v32, W1, b1, u);
  k_gemm<0,0,0><<<dim3(128,1), dim3(256), 0, stream>>>(hist1, pool+PW_HK, bhk, nullptr, wh16, 256, 256, 1.f);
  k_attn<<<dim3(126), dim3(256), 0, stream>>>(wh16, v32, u, pool+PW_1, W2, b2, decv, genv, barv16);
  k_gemm<1,1,0><<<dim3(128,4), dim3(256), 0, stream>>>(barv16, pool+PW_IH, b_ih, b_hh, xg, 256, 1024, 256.f);
  k_scan<0><<<dim3(8), dim3(1024), 0, stream>>>(whh8, xg, h2);
  // classifier: [h1_63 ; h2] (256x256) -> relu GEMM 1024 -> relu GEMM 512 -> 2
  k_gemm<0,0,1><<<dim3(4,4), dim3(256), 0, stream>>>(X, pool+PC_1, C1b, nullptr, y1, 256, 1024, 1.f);
  k_gemm<0,0,1><<<dim3(4,2), dim3(256), 0, stream>>>(y1, pool+PC_2, C2b, nullptr, y2, 1024, 512, 1.f);
  k_out<<<dim3(2), dim3(256), 0, stream>>>(y2, pool+PC_O, Cob, out);
  k_copy<<<dim3(32), dim3(256), 0, stream>>>(sts, label, out);
}